// Round 4
// baseline (190.007 us; speedup 1.0000x reference)
//
#include <hip/hip_runtime.h>
#include <hip/hip_bf16.h>

#define B_      512
#define NI      1152
#define NO      10
#define BT      16
#define NBT     32            // B_/BT
#define NCHUNKS 24
#define NCH     48            // NI/NCHUNKS
#define NGRP    12            // NCH/4 groups of 4 n
#define GPW     3             // groups per wave

typedef __attribute__((ext_vector_type(8))) short bf16x8;
typedef __attribute__((ext_vector_type(4))) float f32x4;
typedef __attribute__((ext_vector_type(8))) unsigned short u16x8;

// workspace (floats / ushorts)
#define SPART_F32  ((size_t)NCHUNKS * NBT * NO * 256)   // 1,966,080 f32 (7.86 MB)
#define OUTSUM_F32 ((size_t)NBT * NO * 256)             //    81,920 f32
#define XB_US      ((size_t)NCHUNKS * NBT * NGRP * 512) // 4,718,592 us (9.44 MB)
// wb: NCHUNKS*NGRP*NO*512 ushorts (2.95 MB)

__device__ inline unsigned short f2bf(float f) {
    __hip_bfloat16 h = __float2bfloat16(f);
    return *reinterpret_cast<unsigned short*>(&h);
}

// x[b][n][j] f32 -> xb granule[((nc*32+bt)*12+g)*64 + nn*16 + bl] of 8 bf16
__global__ __launch_bounds__(256) void cvt_x(
    const float* __restrict__ x, unsigned short* __restrict__ xb)
{
    const int t = blockIdx.x * 256 + threadIdx.x;       // 589,824 threads
    float4 v0 = *reinterpret_cast<const float4*>(x + (size_t)t * 8);
    float4 v1 = *reinterpret_cast<const float4*>(x + (size_t)t * 8 + 4);
    u16x8 u = { f2bf(v0.x), f2bf(v0.y), f2bf(v0.z), f2bf(v0.w),
                f2bf(v1.x), f2bf(v1.y), f2bf(v1.z), f2bf(v1.w) };
    const int b = t / NI, n = t - b * NI;
    const int nc = n / NCH, nl = n - nc * NCH;
    const int g = nl >> 2, nn = nl & 3;
    const int bt = b >> 4, bl = b & 15;
    size_t gr = (((size_t)nc * NBT + bt) * NGRP + g) * 64 + nn * 16 + bl;
    *reinterpret_cast<u16x8*>(xb + gr * 8) = u;
}

// w[o][n][d][j] f32 -> wb granule[((nc*12+g)*10+o)*64 + nn*16 + d] of 8 bf16
__global__ __launch_bounds__(256) void cvt_w(
    const float* __restrict__ w, unsigned short* __restrict__ wb)
{
    const int t = blockIdx.x * 256 + threadIdx.x;       // 184,320 threads
    float4 v0 = *reinterpret_cast<const float4*>(w + (size_t)t * 8);
    float4 v1 = *reinterpret_cast<const float4*>(w + (size_t)t * 8 + 4);
    u16x8 u = { f2bf(v0.x), f2bf(v0.y), f2bf(v0.z), f2bf(v0.w),
                f2bf(v1.x), f2bf(v1.y), f2bf(v1.z), f2bf(v1.w) };
    const int o = t / (NI * 16);
    const int rem = t - o * (NI * 16);
    const int n = rem >> 4, d = rem & 15;
    const int nc = n / NCH, nl = n - nc * NCH;
    const int g = nl >> 2, nn = nl & 3;
    size_t gr = (((size_t)nc * NGRP + g) * NO + o) * 64 + nn * 16 + d;
    *reinterpret_cast<u16x8*>(wb + gr * 8) = u;
}

// One routing iteration. No LDS / barriers in the main loop.
// Lane (b16,hi): A-frag = W[o, n_g+hi, d=b16, :], B-frag = x[b16, n_g+hi, :].
template<bool UNIFORM>
__global__ __launch_bounds__(256, 3) void caps_iter(
    const unsigned short* __restrict__ xb,
    const unsigned short* __restrict__ wb,
    const float* __restrict__ outsum,   // [bt*10+o][64][4] lane-major f32
    float* __restrict__ s_part)         // [nc][bt*10+o][64][4] lane-major f32
{
    __shared__ f32x4 red[4][NO * 64];   // 40,960 B (epilogue only)

    const int tid = threadIdx.x;
    const int w   = tid >> 6;
    const int l   = tid & 63;
    const int hi  = l >> 4;
    const int bt  = blockIdx.x / NCHUNKS;
    const int nc  = blockIdx.x % NCHUNKS;

    f32x4 outf[NO];
    if constexpr (!UNIFORM) {
        #pragma unroll
        for (int o = 0; o < NO; ++o)
            outf[o] = *reinterpret_cast<const f32x4*>(
                outsum + (((size_t)bt * NO + o) * 64 + l) * 4);
    }

    f32x4 sacc[NO];
    #pragma unroll
    for (int o = 0; o < NO; ++o) sacc[o] = (f32x4){0.f, 0.f, 0.f, 0.f};

    const unsigned short* xbase =
        xb + (((size_t)nc * NBT + bt) * NGRP) * 512 + l * 8;
    const unsigned short* wbase =
        wb + ((size_t)nc * NGRP * NO) * 512 + l * 8;

    #pragma unroll 1
    for (int gi = 0; gi < GPW; ++gi) {
        const int g = w * GPW + gi;     // this wave's 4-n group
        bf16x8 bv4 = *reinterpret_cast<const bf16x8*>(xbase + (size_t)g * 512);
        bf16x8 av4[NO];
        #pragma unroll
        for (int o = 0; o < NO; ++o)
            av4[o] = *reinterpret_cast<const bf16x8*>(
                wbase + ((size_t)g * NO + o) * 512);

        if constexpr (UNIFORM) {
            // c uniform: MFMA sums all 4 packed n's directly
            #pragma unroll
            for (int o = 0; o < NO; ++o)
                sacc[o] = __builtin_amdgcn_mfma_f32_16x16x32_bf16(
                    av4[o], bv4, sacc[o], 0, 0, 0);
        } else {
            #pragma unroll
            for (int t = 0; t < 4; ++t) {
                // mask B to k-block t -> single-n x_hat (A stays unmasked)
                bf16x8 bvt = (hi == t) ? bv4 : (bf16x8){0,0,0,0,0,0,0,0};
                float p[NO];
                #pragma unroll
                for (int o = 0; o < NO; ++o) {
                    f32x4 xh = __builtin_amdgcn_mfma_f32_16x16x32_bf16(
                        av4[o], bvt, (f32x4){0.f, 0.f, 0.f, 0.f}, 0, 0, 0);
                    float pp = outf[o][0] * xh[0];
                    pp = fmaf(outf[o][1], xh[1], pp);
                    pp = fmaf(outf[o][2], xh[2], pp);
                    pp = fmaf(outf[o][3], xh[3], pp);
                    pp += __shfl_xor(pp, 16, 64);
                    pp += __shfl_xor(pp, 32, 64);
                    p[o] = pp;
                }
                float sum = 0.f;
                #pragma unroll
                for (int o = 0; o < NO; ++o) { p[o] = __expf(p[o]); sum += p[o]; }
                const float rs = __builtin_amdgcn_rcpf(sum);
                #pragma unroll
                for (int o = 0; o < NO; ++o) {
                    const float cc = p[o] * rs;
                    f32x4 xh = __builtin_amdgcn_mfma_f32_16x16x32_bf16(
                        av4[o], bvt, (f32x4){0.f, 0.f, 0.f, 0.f}, 0, 0, 0);
                    sacc[o][0] = fmaf(cc, xh[0], sacc[o][0]);
                    sacc[o][1] = fmaf(cc, xh[1], sacc[o][1]);
                    sacc[o][2] = fmaf(cc, xh[2], sacc[o][2]);
                    sacc[o][3] = fmaf(cc, xh[3], sacc[o][3]);
                }
            }
        }
    }

    // epilogue: cross-wave reduce (lane-consecutive LDS = conflict-free)
    const float sc = UNIFORM ? 0.1f : 1.0f;
    #pragma unroll
    for (int o = 0; o < NO; ++o) {
        f32x4 v = { sacc[o][0] * sc, sacc[o][1] * sc,
                    sacc[o][2] * sc, sacc[o][3] * sc };
        red[w][o * 64 + l] = v;
    }
    __syncthreads();
    const f32x4* rp = &red[0][0];
    float* dst = s_part + (((size_t)nc * NBT + bt) * NO) * 256;
    for (int g2 = tid; g2 < NO * 64; g2 += 256) {
        f32x4 a0 = rp[g2], a1 = rp[640 + g2], a2 = rp[1280 + g2], a3 = rp[1920 + g2];
        f32x4 s;
        #pragma unroll
        for (int q = 0; q < 4; ++q) s[q] = (a0[q] + a1[q]) + (a2[q] + a3[q]);
        *reinterpret_cast<f32x4*>(dst + (size_t)g2 * 4) = s;
    }
}

// Reduce chunks + squash. Thread t in block bo=(bt*10+o): t = l*4+q, d = hi*4+q.
template<int MODE>
__global__ __launch_bounds__(256) void caps_squash(
    const float* __restrict__ s_part,
    float* __restrict__ outsum,
    float* __restrict__ dout)
{
    __shared__ float sq[256];
    const int bo = blockIdx.x;
    const int t  = threadIdx.x;

    float s = 0.f;
    #pragma unroll
    for (int nc = 0; nc < NCHUNKS; ++nc)
        s += s_part[((size_t)nc * NBT * NO + bo) * 256 + t];

    float n2 = s * s;
    n2 += __shfl_xor(n2, 1, 64);
    n2 += __shfl_xor(n2, 2, 64);       // q-group reduced
    sq[t] = n2;
    __syncthreads();
    const int base = t & 63;
    n2 = (sq[base] + sq[64 + base]) + (sq[128 + base] + sq[192 + base]);

    const float norm  = sqrtf(n2);
    const float scale = n2 / ((1.f + n2) * (norm + 1e-8f));
    const float v = scale * s;

    if constexpr (MODE == 0) {
        outsum[(size_t)bo * 256 + t] = v;
    } else if constexpr (MODE == 1) {
        outsum[(size_t)bo * 256 + t] += v;
    } else {
        const int bt = bo / NO, o = bo - bt * NO;
        const int b16 = (t >> 2) & 15, hi = t >> 6, q = t & 3;
        dout[((size_t)(bt * BT + b16) * NO + o) * 16 + hi * 4 + q] = v;
    }
}

extern "C" void kernel_launch(void* const* d_in, const int* in_sizes, int n_in,
                              void* d_out, int out_size, void* d_ws, size_t ws_size,
                              hipStream_t stream) {
    const float* x = (const float*)d_in[0];   // [512][1152][8]
    const float* w = (const float*)d_in[1];   // [10][1152][16][8]
    float* out = (float*)d_out;               // [512][10][16]

    float* s_part          = (float*)d_ws;
    float* outsum          = s_part + SPART_F32;
    unsigned short* xb     = (unsigned short*)(outsum + OUTSUM_F32);
    unsigned short* wb     = xb + XB_US;      // total ws ~20.6 MB

    cvt_x<<<dim3(2304), dim3(256), 0, stream>>>(x, xb);
    cvt_w<<<dim3(720),  dim3(256), 0, stream>>>(w, wb);

    dim3 gI(NBT * NCHUNKS), bI(256);          // 768 blocks = 3/CU exactly
    dim3 gS(NBT * NO), bS(256);               // 320 blocks

    caps_iter<true ><<<gI, bI, 0, stream>>>(xb, wb, nullptr, s_part);
    caps_squash<0><<<gS, bS, 0, stream>>>(s_part, outsum, nullptr);
    caps_iter<false><<<gI, bI, 0, stream>>>(xb, wb, outsum, s_part);
    caps_squash<1><<<gS, bS, 0, stream>>>(s_part, outsum, nullptr);
    caps_iter<false><<<gI, bI, 0, stream>>>(xb, wb, outsum, s_part);
    caps_squash<2><<<gS, bS, 0, stream>>>(s_part, nullptr, out);
}